// Round 9
// baseline (257.451 us; speedup 1.0000x reference)
//
#include <hip/hip_runtime.h>

#define Bsz 8
#define Tn  2048
#define Cn  1024
#define Hn  16
#define Sn  64
#define Mn  (Bsz * Tn)   // 16384
#define NC  32
#define LCH (Tn / NC)    // 64
#define Kd  1024
#define NKT (Kd / 64)    // 16 K-tiles of 64

typedef __attribute__((ext_vector_type(8))) short bf16x8;
typedef __attribute__((ext_vector_type(4))) float f32x4;

__device__ __forceinline__ unsigned short f2bf(float f) {
  union { float f; unsigned int u; } v;
  v.f = f;
  unsigned int r = (v.u + 0x7FFFu + ((v.u >> 16) & 1u)) >> 16;
  return (unsigned short)r;
}
__device__ __forceinline__ float bf2f(unsigned short u) {
  union { unsigned int u; float f; } v;
  v.u = ((unsigned int)u) << 16;
  return v.f;
}

// ---------------- weight fp32 -> bf16 ----------------
__global__ void wconv_kernel(const float* __restrict__ Wk, const float* __restrict__ Wv,
                             const float* __restrict__ Wr, const float* __restrict__ Wo,
                             unsigned short* __restrict__ out) {
  int i = blockIdx.x * blockDim.x + threadIdx.x;
  int which = i >> 18;
  int off = (i & 0x3FFFF) * 4;
  const float* src = which == 0 ? Wk : which == 1 ? Wv : which == 2 ? Wr : Wo;
  float4 f = *(const float4*)(src + off);
  ushort4 o;
  o.x = f2bf(f.x); o.y = f2bf(f.y); o.z = f2bf(f.z); o.w = f2bf(f.w);
  *(ushort4*)(out + (size_t)which * (Cn * Cn) + off) = o;
}

// ---------------- fused time-shift mix ----------------
__global__ void mix3_kernel(const float* __restrict__ x,
                            const float* __restrict__ tmk, const float* __restrict__ tmv,
                            const float* __restrict__ tmr,
                            unsigned short* __restrict__ ok, unsigned short* __restrict__ ov,
                            unsigned short* __restrict__ orr) {
  int idx = blockIdx.x * blockDim.x + threadIdx.x;
  int c4 = idx & (Cn / 4 - 1);
  int bt = idx >> 8;
  int t = bt & (Tn - 1);
  size_t base = (size_t)bt * Cn + c4 * 4;
  float4 xv = *(const float4*)(x + base);
  float4 xxv = {0.f, 0.f, 0.f, 0.f};
  if (t != 0) xxv = *(const float4*)(x + base - Cn);
  float4 dx = {xv.x - xxv.x, xv.y - xxv.y, xv.z - xxv.z, xv.w - xxv.w};
  float4 tk = *(const float4*)(tmk + c4 * 4);
  float4 tv = *(const float4*)(tmv + c4 * 4);
  float4 tr = *(const float4*)(tmr + c4 * 4);
  ushort4 a, b, c;
  a.x = f2bf(xxv.x + tk.x * dx.x); a.y = f2bf(xxv.y + tk.y * dx.y);
  a.z = f2bf(xxv.z + tk.z * dx.z); a.w = f2bf(xxv.w + tk.w * dx.w);
  b.x = f2bf(xxv.x + tv.x * dx.x); b.y = f2bf(xxv.y + tv.y * dx.y);
  b.z = f2bf(xxv.z + tv.z * dx.z); b.w = f2bf(xxv.w + tv.w * dx.w);
  c.x = f2bf(xxv.x + tr.x * dx.x); c.y = f2bf(xxv.y + tr.y * dx.y);
  c.z = f2bf(xxv.z + tr.z * dx.z); c.w = f2bf(xxv.w + tr.w * dx.w);
  *(ushort4*)(ok + base) = a;
  *(ushort4*)(ov + base) = b;
  *(ushort4*)(orr + base) = c;
}

// ---------------- 256x256 GEMM, 8-phase, band-ordered counted vmcnt ----------------
// C[m,n] = sum_k A[m,k]*Bt[n,k]; M=16384, N=K=1024.
// LDS dbuf x { A 256x64 (32KB) | B 256x64 (32KB) } = 128KB.
// Granule (r,c): physical slot = c ^ (r&7), byte = r*128 + slot*16.
// Staging: per-wave gload = 8-row slab (wave-uniform LDS base + lane*16 — the
// hardware rule; per-lane source address carries the inverse swizzle).
// Per K-tile, each wave issues 8 slabs at P1 PRE in order [B0..B3, A0, A2, A1, A3].
// Drains: P3 POST vmcnt(2) -> B+A0+A2 of kt+1 ready for next P0 (2 phases old);
//         P0 POST vmcnt(0) -> A1,A3 stragglers (3 phases old) ready for P1.
__device__ __forceinline__ void gload_lds16(const void* g, void* l) {
  __builtin_amdgcn_global_load_lds((const __attribute__((address_space(1))) void*)g,
                                   (__attribute__((address_space(3))) void*)l, 16, 0, 0);
}

// One phase: (H = m-half, KS = k-half). LOADB: load B frags.
// PRE: staging issue (before mid barrier). POST: counted vmcnt (after MFMA).
#define PHASE(H, KS, LOADB, PRE, POST)                                             \
  {                                                                                \
    _Pragma("unroll") for (int mi4 = 0; mi4 < 4; ++mi4) {                          \
      const int row = wm * 128 + (H) * 64 + mi4 * 16 + l15;                        \
      aF[mi4] = *(const bf16x8*)(ldsc + dbase + row * 128 +                        \
                                 ((((KS) * 4 + lg) ^ (row & 7)) << 4));            \
    }                                                                              \
    if (LOADB) {                                                                   \
      _Pragma("unroll") for (int nj = 0; nj < 4; ++nj) {                           \
        const int row = wn * 64 + nj * 16 + l15;                                   \
        bF[nj] = *(const bf16x8*)(ldsc + dbase + 32768 + row * 128 +               \
                                  ((((KS) * 4 + lg) ^ (row & 7)) << 4));           \
      }                                                                            \
    }                                                                              \
    PRE;                                                                           \
    __builtin_amdgcn_s_barrier();                                                  \
    asm volatile("s_waitcnt lgkmcnt(0)" ::: "memory");                             \
    __builtin_amdgcn_sched_barrier(0);                                             \
    __builtin_amdgcn_s_setprio(1);                                                 \
    _Pragma("unroll") for (int mi4 = 0; mi4 < 4; ++mi4)                            \
      _Pragma("unroll") for (int nj = 0; nj < 4; ++nj)                             \
        acc[(H) * 4 + mi4][nj] = __builtin_amdgcn_mfma_f32_16x16x32_bf16(          \
            aF[mi4], bF[nj], acc[(H) * 4 + mi4][nj], 0, 0, 0);                     \
    __builtin_amdgcn_s_setprio(0);                                                 \
    POST;                                                                          \
    __builtin_amdgcn_s_barrier();                                                  \
  }

template <bool OUTBF16>
__global__ __launch_bounds__(512, 2) void gemm8p(const unsigned short* __restrict__ A,
                                                 const unsigned short* __restrict__ Bt,
                                                 void* __restrict__ Cm) {
  __shared__ unsigned short lds[65536];
  char* ldsc = (char*)lds;
  const int tid = threadIdx.x;
  const int wid = tid >> 6, lane = tid & 63;
  const int wm = wid >> 2, wn = wid & 3;
  const int l15 = lane & 15, lg = lane >> 4;
  int bid = ((int)blockIdx.x & 7) * 32 + ((int)blockIdx.x >> 3);  // XCD-bijective
  const int mt = bid >> 2, nt = bid & 3;
  const int m0 = mt * 256, n0 = nt * 256;

  const unsigned short* Ag = A + (size_t)m0 * Kd;
  const unsigned short* Bg = Bt + (size_t)n0 * Kd;

  // One gload/wave: 8-row slab of a 64-row band. LDS dest = wave-uniform base +
  // lane*16 (linear, per HW rule); per-lane global source pre-inverse-swizzled.
  auto stageSlice = [&](const unsigned short* gbase, int ktt, int band, int Loff) {
    const int r = band * 64 + wid * 8 + (lane >> 3);
    const int c = (lane & 7) ^ (r & 7);
    gload_lds16(gbase + (size_t)r * Kd + ktt * 64 + c * 8,
                ldsc + Loff + (band * 64 + wid * 8) * 128 + lane * 16);
  };
  // per-wave issue order: [B0,B1,B2,B3, A0, A2, A1, A3]
  auto stage8 = [&](int ktt, int base) {
    stageSlice(Bg, ktt, 0, base + 32768);
    stageSlice(Bg, ktt, 1, base + 32768);
    stageSlice(Bg, ktt, 2, base + 32768);
    stageSlice(Bg, ktt, 3, base + 32768);
    stageSlice(Ag, ktt, 0, base);
    stageSlice(Ag, ktt, 2, base);
    stageSlice(Ag, ktt, 1, base);
    stageSlice(Ag, ktt, 3, base);
  };

  f32x4 acc[8][4] = {};
  bf16x8 aF[4], bF[4];

  // prologue: K-tile 0 into buf0; drain all but the A1,A3 stragglers
  stage8(0, 0);
  asm volatile("s_waitcnt vmcnt(2)" ::: "memory");
  __builtin_amdgcn_s_barrier();

  for (int kt = 0; kt < NKT; ++kt) {
    const int dbase = (kt & 1) << 16;
    const int nd = dbase ^ 65536;
    const bool st = (kt + 1 < NKT);
    // P0 (h0,k0): drain A1,A3 stragglers (3 phases old) for P1's reads
    PHASE(0, 0, 1, ;, asm volatile("s_waitcnt vmcnt(0)" ::: "memory"))
    // P1 (h1,k0): issue kt+1's 8 slabs into the other dbuf
    PHASE(1, 0, 0, if (st) stage8(kt + 1, nd), ;)
    // P2 (h1,k1)
    PHASE(1, 1, 1, ;, ;)
    // P3 (h0,k1): drain 6 oldest (B + A0 + A2 of kt+1), keep A1,A3 in flight
    PHASE(0, 1, 0, ;, asm volatile("s_waitcnt vmcnt(2)" ::: "memory"))
  }

  if (OUTBF16) {
    // per-wave LDS transpose -> 128B-row coalesced stores
    char* tb = ldsc + wid * 16384;
#pragma unroll
    for (int mi = 0; mi < 8; ++mi)
#pragma unroll
      for (int nj = 0; nj < 4; ++nj)
#pragma unroll
        for (int rr = 0; rr < 4; ++rr) {
          const int row = mi * 16 + lg * 4 + rr;
          const int col = nj * 16 + l15;
          *(unsigned short*)(tb + row * 128 + ((col * 2) ^ ((row & 7) << 4))) =
              f2bf(acc[mi][nj][rr]);
        }
    asm volatile("s_waitcnt lgkmcnt(0)" ::: "memory");
    __builtin_amdgcn_sched_barrier(0);
    const int orl = lane >> 3, och = lane & 7;
#pragma unroll
    for (int it = 0; it < 16; ++it) {
      const int row = it * 8 + orl;
      uint4 vv = *(const uint4*)(tb + row * 128 + ((och * 16) ^ ((row & 7) << 4)));
      const int gr = m0 + wm * 128 + row;
      const int gc = n0 + wn * 64 + och * 8;
      *(uint4*)((unsigned short*)Cm + (size_t)gr * Cn + gc) = vv;
    }
  } else {
#pragma unroll
    for (int mi = 0; mi < 8; ++mi)
#pragma unroll
      for (int nj = 0; nj < 4; ++nj)
#pragma unroll
        for (int rr = 0; rr < 4; ++rr) {
          const int row = m0 + wm * 128 + mi * 16 + lg * 4 + rr;
          const int col = n0 + wn * 64 + nj * 16 + l15;
          ((float*)Cm)[(size_t)row * Cn + col] = acc[mi][nj][rr];
        }
  }
}

// ---------------- chunked scan (bf16 in/out, fp32 state) ----------------
__global__ void scan_phase1(const unsigned short* __restrict__ k,
                            const unsigned short* __restrict__ v,
                            const float* __restrict__ td, float* __restrict__ cs) {
  int blk = blockIdx.x;
  int c = blk & (NC - 1);
  int bh = blk >> 5;
  int b = bh >> 4;
  int h = bh & 15;
  int s = threadIdx.x;
  float decay = expf(td[h * Sn + s]);
  size_t base = ((size_t)(b * Tn + c * LCH)) * Cn + h * Sn + s;
  float st = 0.f;
#pragma unroll 8
  for (int i = 0; i < LCH; ++i) {
    float kv = bf2f(k[base]) * bf2f(v[base]);
    st = kv + decay * st;
    base += Cn;
  }
  cs[(size_t)blk * Sn + s] = st;
}

__global__ void scan_phase2(const float* __restrict__ td, float* __restrict__ cs) {
  int bh = blockIdx.x;
  int h = bh & 15;
  int s = threadIdx.x;
  float dL = expf(td[h * Sn + s] * (float)LCH);
  float carry = 0.f;
  for (int c = 0; c < NC; ++c) {
    size_t idx = ((size_t)bh * NC + c) * Sn + s;
    float sc = cs[idx];
    cs[idx] = carry;
    carry = sc + dL * carry;
  }
}

__global__ void scan_phase3(const unsigned short* __restrict__ k,
                            const unsigned short* __restrict__ v,
                            const unsigned short* __restrict__ r,
                            const float* __restrict__ td, const float* __restrict__ tf,
                            const float* __restrict__ cs,
                            unsigned short* __restrict__ out) {
  int blk = blockIdx.x;
  int c = blk & (NC - 1);
  int bh = blk >> 5;
  int b = bh >> 4;
  int h = bh & 15;
  int s = threadIdx.x;
  float decay = expf(td[h * Sn + s]);
  float first = tf[h * Sn + s];
  float st = cs[(size_t)blk * Sn + s];
  size_t base = ((size_t)(b * Tn + c * LCH)) * Cn + h * Sn + s;
#pragma unroll 8
  for (int i = 0; i < LCH; ++i) {
    float kv = bf2f(k[base]) * bf2f(v[base]);
    st = kv + decay * st;
    out[base] = f2bf(bf2f(r[base]) * (first * kv + st));
    base += Cn;
  }
}

// ---------------- layernorm (bf16 in) -> bf16 ----------------
__global__ __launch_bounds__(256) void ln_kernel(const unsigned short* __restrict__ in,
                                                 const float* __restrict__ g,
                                                 const float* __restrict__ bb,
                                                 unsigned short* __restrict__ out) {
  int row = blockIdx.x;
  int tid = threadIdx.x;
  size_t base = (size_t)row * Cn + tid * 4;
  ushort4 uv = *(const ushort4*)(in + base);
  float4 xv = {bf2f(uv.x), bf2f(uv.y), bf2f(uv.z), bf2f(uv.w)};
  float sum = xv.x + xv.y + xv.z + xv.w;
  float ss = xv.x * xv.x + xv.y * xv.y + xv.z * xv.z + xv.w * xv.w;
#pragma unroll
  for (int off = 32; off >= 1; off >>= 1) {
    sum += __shfl_down(sum, off, 64);
    ss += __shfl_down(ss, off, 64);
  }
  __shared__ float s1[4], s2[4];
  if ((tid & 63) == 0) { s1[tid >> 6] = sum; s2[tid >> 6] = ss; }
  __syncthreads();
  sum = s1[0] + s1[1] + s1[2] + s1[3];
  ss = s2[0] + s2[1] + s2[2] + s2[3];
  float mu = sum * (1.f / Cn);
  float var = ss * (1.f / Cn) - mu * mu;
  float rstd = rsqrtf(var + 1e-5f);
  float4 gv = *(const float4*)(g + tid * 4);
  float4 bv = *(const float4*)(bb + tid * 4);
  ushort4 o;
  o.x = f2bf((xv.x - mu) * rstd * gv.x + bv.x);
  o.y = f2bf((xv.y - mu) * rstd * gv.y + bv.y);
  o.z = f2bf((xv.z - mu) * rstd * gv.z + bv.z);
  o.w = f2bf((xv.w - mu) * rstd * gv.w + bv.w);
  *(ushort4*)(out + base) = o;
}

extern "C" void kernel_launch(void* const* d_in, const int* in_sizes, int n_in,
                              void* d_out, int out_size, void* d_ws, size_t ws_size,
                              hipStream_t stream) {
  const float* x   = (const float*)d_in[0];
  const float* tmk = (const float*)d_in[1];
  const float* tmv = (const float*)d_in[2];
  const float* tmr = (const float*)d_in[3];
  const float* td  = (const float*)d_in[4];
  const float* tf  = (const float*)d_in[5];
  const float* Wk  = (const float*)d_in[6];
  const float* Wv  = (const float*)d_in[7];
  const float* Wr  = (const float*)d_in[8];
  const float* Wo  = (const float*)d_in[9];
  const float* lng = (const float*)d_in[10];
  const float* lnb = (const float*)d_in[11];
  float* out = (float*)d_out;

  char* ws = (char*)d_ws;
  const size_t MB = 1024 * 1024;
  unsigned short* wbf  = (unsigned short*)(ws);              // 8 MB (4 weights bf16)
  unsigned short* xk   = (unsigned short*)(ws + 8 * MB);     // 32 MB
  unsigned short* xv_  = (unsigned short*)(ws + 40 * MB);    // 32 MB
  unsigned short* xr   = (unsigned short*)(ws + 72 * MB);    // 32 MB
  unsigned short* bufK = (unsigned short*)(ws + 104 * MB);   // 32 MB
  unsigned short* bufV = (unsigned short*)(ws + 136 * MB);   // 32 MB
  unsigned short* bufR = (unsigned short*)(ws + 168 * MB);   // 32 MB
  unsigned short* preLN = xk;                                // reuse
  unsigned short* lnout = xv_;                               // reuse
  float* chunkS = (float*)(ws + 200 * MB);                   // 1 MB

  const int gemm_grid = (Mn / 256) * (Cn / 256);  // 256
  const int mix_grid = Mn * (Cn / 4) / 256;       // 16384

  wconv_kernel<<<4 * Cn * Cn / 4 / 256, 256, 0, stream>>>(Wk, Wv, Wr, Wo, wbf);
  mix3_kernel<<<mix_grid, 256, 0, stream>>>(x, tmk, tmv, tmr, xk, xv_, xr);

  gemm8p<true><<<gemm_grid, 512, 0, stream>>>(xk,  wbf + 0 * (size_t)Cn * Cn, bufK);
  gemm8p<true><<<gemm_grid, 512, 0, stream>>>(xv_, wbf + 1 * (size_t)Cn * Cn, bufV);
  gemm8p<true><<<gemm_grid, 512, 0, stream>>>(xr,  wbf + 2 * (size_t)Cn * Cn, bufR);

  scan_phase1<<<Bsz * Hn * NC, 64, 0, stream>>>(bufK, bufV, td, chunkS);
  scan_phase2<<<Bsz * Hn, 64, 0, stream>>>(td, chunkS);
  scan_phase3<<<Bsz * Hn * NC, 64, 0, stream>>>(bufK, bufV, bufR, td, tf, chunkS, preLN);

  ln_kernel<<<Mn, 256, 0, stream>>>(preLN, lng, lnb, lnout);

  gemm8p<false><<<gemm_grid, 512, 0, stream>>>(lnout, wbf + 3 * (size_t)Cn * Cn, out);

  (void)in_sizes; (void)n_in; (void)out_size; (void)ws_size;
}

// Round 10
// 252.148 us; speedup vs baseline: 1.0210x; 1.0210x over previous
//
#include <hip/hip_runtime.h>

#define Bsz 8
#define Tn  2048
#define Cn  1024
#define Hn  16
#define Sn  64
#define Mn  (Bsz * Tn)   // 16384
#define NC  32
#define LCH (Tn / NC)    // 64
#define Kd  1024
#define NKT (Kd / 64)    // 16 K-tiles of 64

typedef __attribute__((ext_vector_type(8))) short bf16x8;
typedef __attribute__((ext_vector_type(4))) float f32x4;

__device__ __forceinline__ unsigned short f2bf(float f) {
  union { float f; unsigned int u; } v;
  v.f = f;
  unsigned int r = (v.u + 0x7FFFu + ((v.u >> 16) & 1u)) >> 16;
  return (unsigned short)r;
}
__device__ __forceinline__ float bf2f(unsigned short u) {
  union { unsigned int u; float f; } v;
  v.u = ((unsigned int)u) << 16;
  return v.f;
}

// ---------------- weight fp32 -> bf16 ----------------
__global__ void wconv_kernel(const float* __restrict__ Wk, const float* __restrict__ Wv,
                             const float* __restrict__ Wr, const float* __restrict__ Wo,
                             unsigned short* __restrict__ out) {
  int i = blockIdx.x * blockDim.x + threadIdx.x;
  int which = i >> 18;
  int off = (i & 0x3FFFF) * 4;
  const float* src = which == 0 ? Wk : which == 1 ? Wv : which == 2 ? Wr : Wo;
  float4 f = *(const float4*)(src + off);
  ushort4 o;
  o.x = f2bf(f.x); o.y = f2bf(f.y); o.z = f2bf(f.z); o.w = f2bf(f.w);
  *(ushort4*)(out + (size_t)which * (Cn * Cn) + off) = o;
}

// ---------------- fused time-shift mix ----------------
__global__ void mix3_kernel(const float* __restrict__ x,
                            const float* __restrict__ tmk, const float* __restrict__ tmv,
                            const float* __restrict__ tmr,
                            unsigned short* __restrict__ ok, unsigned short* __restrict__ ov,
                            unsigned short* __restrict__ orr) {
  int idx = blockIdx.x * blockDim.x + threadIdx.x;
  int c4 = idx & (Cn / 4 - 1);
  int bt = idx >> 8;
  int t = bt & (Tn - 1);
  size_t base = (size_t)bt * Cn + c4 * 4;
  float4 xv = *(const float4*)(x + base);
  float4 xxv = {0.f, 0.f, 0.f, 0.f};
  if (t != 0) xxv = *(const float4*)(x + base - Cn);
  float4 dx = {xv.x - xxv.x, xv.y - xxv.y, xv.z - xxv.z, xv.w - xxv.w};
  float4 tk = *(const float4*)(tmk + c4 * 4);
  float4 tv = *(const float4*)(tmv + c4 * 4);
  float4 tr = *(const float4*)(tmr + c4 * 4);
  ushort4 a, b, c;
  a.x = f2bf(xxv.x + tk.x * dx.x); a.y = f2bf(xxv.y + tk.y * dx.y);
  a.z = f2bf(xxv.z + tk.z * dx.z); a.w = f2bf(xxv.w + tk.w * dx.w);
  b.x = f2bf(xxv.x + tv.x * dx.x); b.y = f2bf(xxv.y + tv.y * dx.y);
  b.z = f2bf(xxv.z + tv.z * dx.z); b.w = f2bf(xxv.w + tv.w * dx.w);
  c.x = f2bf(xxv.x + tr.x * dx.x); c.y = f2bf(xxv.y + tr.y * dx.y);
  c.z = f2bf(xxv.z + tr.z * dx.z); c.w = f2bf(xxv.w + tr.w * dx.w);
  *(ushort4*)(ok + base) = a;
  *(ushort4*)(ov + base) = b;
  *(ushort4*)(orr + base) = c;
}

// ---------------- 256x256 GEMM, 1 barrier/K-tile, compiler-scheduled body ----------------
// C[m,n] = sum_k A[m,k]*Bt[n,k]; M=16384, N=K=1024.
// LDS dbuf x { A 256x64 (32KB) | B 256x64 (32KB) } = 128KB.
// Granule (r,c): physical slot = c ^ (r&7), byte = r*128 + slot*16 (conflict-free reads).
// Staging: 8-row slab per gload (wave-uniform LDS base + lane*16, per HW rule);
// per-lane global source carries the inverse swizzle. Staging for kt+1 issued at the
// TOP of kt's body; __syncthreads() at the END drains it (~2500cyc slack -> cheap).
// NO intra-K-tile barriers / manual lgkm / sched pins: the compiler interleaves the
// 24 ds_reads with the 64 MFMAs using counted lgkmcnt (its documented strength).
__device__ __forceinline__ void gload_lds16(const void* g, void* l) {
  __builtin_amdgcn_global_load_lds((const __attribute__((address_space(1))) void*)g,
                                   (__attribute__((address_space(3))) void*)l, 16, 0, 0);
}

#define LDA(dst, H, KS)                                                            \
  _Pragma("unroll") for (int mi4 = 0; mi4 < 4; ++mi4) {                            \
    const int row = wm * 128 + (H) * 64 + mi4 * 16 + l15;                          \
    dst[mi4] = *(const bf16x8*)(ldsc + dbase + row * 128 +                         \
                                ((((KS) * 4 + lg) ^ (row & 7)) << 4));             \
  }
#define LDB(dst, KS)                                                               \
  _Pragma("unroll") for (int nj = 0; nj < 4; ++nj) {                               \
    const int row = wn * 64 + nj * 16 + l15;                                       \
    dst[nj] = *(const bf16x8*)(ldsc + dbase + 32768 + row * 128 +                  \
                               ((((KS) * 4 + lg) ^ (row & 7)) << 4));              \
  }
#define MFMA16(H, AV, BV)                                                          \
  _Pragma("unroll") for (int mi4 = 0; mi4 < 4; ++mi4)                              \
    _Pragma("unroll") for (int nj = 0; nj < 4; ++nj)                               \
      acc[(H) * 4 + mi4][nj] = __builtin_amdgcn_mfma_f32_16x16x32_bf16(            \
          AV[mi4], BV[nj], acc[(H) * 4 + mi4][nj], 0, 0, 0);

template <bool OUTBF16>
__global__ __launch_bounds__(512, 2) void gemm1b(const unsigned short* __restrict__ A,
                                                 const unsigned short* __restrict__ Bt,
                                                 void* __restrict__ Cm) {
  __shared__ unsigned short lds[65536];
  char* ldsc = (char*)lds;
  const int tid = threadIdx.x;
  const int wid = tid >> 6, lane = tid & 63;
  const int wm = wid >> 2, wn = wid & 3;
  const int l15 = lane & 15, lg = lane >> 4;
  int bid = ((int)blockIdx.x & 7) * 32 + ((int)blockIdx.x >> 3);  // XCD-bijective
  const int mt = bid >> 2, nt = bid & 3;
  const int m0 = mt * 256, n0 = nt * 256;

  const unsigned short* Ag = A + (size_t)m0 * Kd;
  const unsigned short* Bg = Bt + (size_t)n0 * Kd;

  // One gload/wave: 8-row slab. LDS dest = wave-uniform base + lane*16 (linear);
  // per-lane global source pre-inverse-swizzled.
  auto stageSlice = [&](const unsigned short* gbase, int ktt, int band, int Loff) {
    const int r = band * 64 + wid * 8 + (lane >> 3);
    const int c = (lane & 7) ^ (r & 7);
    gload_lds16(gbase + (size_t)r * Kd + ktt * 64 + c * 8,
                ldsc + Loff + (band * 64 + wid * 8) * 128 + lane * 16);
  };
  auto stage8 = [&](int ktt, int base) {
#pragma unroll
    for (int band = 0; band < 4; ++band) stageSlice(Ag, ktt, band, base);
#pragma unroll
    for (int band = 0; band < 4; ++band) stageSlice(Bg, ktt, band, base + 32768);
  };

  f32x4 acc[8][4] = {};

  // prologue: K-tile 0 into buf0 (implicit vmcnt(0) in syncthreads publishes it)
  stage8(0, 0);
  __syncthreads();

#pragma unroll 2
  for (int kt = 0; kt < NKT; ++kt) {
    const int dbase = (kt & 1) << 16;
    const int nd = dbase ^ 65536;
    if (kt + 1 < NKT) stage8(kt + 1, nd);

    // 4 sub-phases, no barriers, 1-phase read lookahead in source order:
    bf16x8 a0[4], a1[4], a2[4], a3[4], b0[4], b1[4];
    LDA(a0, 0, 0)
    LDB(b0, 0)
    LDA(a1, 1, 0)
    MFMA16(0, a0, b0)
    LDA(a2, 1, 1)
    LDB(b1, 1)
    MFMA16(1, a1, b0)
    LDA(a3, 0, 1)
    MFMA16(1, a2, b1)
    MFMA16(0, a3, b1)

    __syncthreads();  // drains this body's staging (issued ~2500cyc ago) + publishes
  }

  if (OUTBF16) {
    // per-wave LDS transpose -> 128B-row coalesced stores
    char* tb = ldsc + wid * 16384;
#pragma unroll
    for (int mi = 0; mi < 8; ++mi)
#pragma unroll
      for (int nj = 0; nj < 4; ++nj)
#pragma unroll
        for (int rr = 0; rr < 4; ++rr) {
          const int row = mi * 16 + lg * 4 + rr;
          const int col = nj * 16 + l15;
          *(unsigned short*)(tb + row * 128 + ((col * 2) ^ ((row & 7) << 4))) =
              f2bf(acc[mi][nj][rr]);
        }
    asm volatile("s_waitcnt lgkmcnt(0)" ::: "memory");
    __builtin_amdgcn_sched_barrier(0);
    const int orl = lane >> 3, och = lane & 7;
#pragma unroll
    for (int it = 0; it < 16; ++it) {
      const int row = it * 8 + orl;
      uint4 vv = *(const uint4*)(tb + row * 128 + ((och * 16) ^ ((row & 7) << 4)));
      const int gr = m0 + wm * 128 + row;
      const int gc = n0 + wn * 64 + och * 8;
      *(uint4*)((unsigned short*)Cm + (size_t)gr * Cn + gc) = vv;
    }
  } else {
#pragma unroll
    for (int mi = 0; mi < 8; ++mi)
#pragma unroll
      for (int nj = 0; nj < 4; ++nj)
#pragma unroll
        for (int rr = 0; rr < 4; ++rr) {
          const int row = m0 + wm * 128 + mi * 16 + lg * 4 + rr;
          const int col = n0 + wn * 64 + nj * 16 + l15;
          ((float*)Cm)[(size_t)row * Cn + col] = acc[mi][nj][rr];
        }
  }
}

// ---------------- chunked scan (bf16 in/out, fp32 state) ----------------
__global__ void scan_phase1(const unsigned short* __restrict__ k,
                            const unsigned short* __restrict__ v,
                            const float* __restrict__ td, float* __restrict__ cs) {
  int blk = blockIdx.x;
  int c = blk & (NC - 1);
  int bh = blk >> 5;
  int b = bh >> 4;
  int h = bh & 15;
  int s = threadIdx.x;
  float decay = expf(td[h * Sn + s]);
  size_t base = ((size_t)(b * Tn + c * LCH)) * Cn + h * Sn + s;
  float st = 0.f;
#pragma unroll 8
  for (int i = 0; i < LCH; ++i) {
    float kv = bf2f(k[base]) * bf2f(v[base]);
    st = kv + decay * st;
    base += Cn;
  }
  cs[(size_t)blk * Sn + s] = st;
}

__global__ void scan_phase2(const float* __restrict__ td, float* __restrict__ cs) {
  int bh = blockIdx.x;
  int h = bh & 15;
  int s = threadIdx.x;
  float dL = expf(td[h * Sn + s] * (float)LCH);
  float carry = 0.f;
  for (int c = 0; c < NC; ++c) {
    size_t idx = ((size_t)bh * NC + c) * Sn + s;
    float sc = cs[idx];
    cs[idx] = carry;
    carry = sc + dL * carry;
  }
}

__global__ void scan_phase3(const unsigned short* __restrict__ k,
                            const unsigned short* __restrict__ v,
                            const unsigned short* __restrict__ r,
                            const float* __restrict__ td, const float* __restrict__ tf,
                            const float* __restrict__ cs,
                            unsigned short* __restrict__ out) {
  int blk = blockIdx.x;
  int c = blk & (NC - 1);
  int bh = blk >> 5;
  int b = bh >> 4;
  int h = bh & 15;
  int s = threadIdx.x;
  float decay = expf(td[h * Sn + s]);
  float first = tf[h * Sn + s];
  float st = cs[(size_t)blk * Sn + s];
  size_t base = ((size_t)(b * Tn + c * LCH)) * Cn + h * Sn + s;
#pragma unroll 8
  for (int i = 0; i < LCH; ++i) {
    float kv = bf2f(k[base]) * bf2f(v[base]);
    st = kv + decay * st;
    out[base] = f2bf(bf2f(r[base]) * (first * kv + st));
    base += Cn;
  }
}

// ---------------- layernorm (bf16 in) -> bf16 ----------------
__global__ __launch_bounds__(256) void ln_kernel(const unsigned short* __restrict__ in,
                                                 const float* __restrict__ g,
                                                 const float* __restrict__ bb,
                                                 unsigned short* __restrict__ out) {
  int row = blockIdx.x;
  int tid = threadIdx.x;
  size_t base = (size_t)row * Cn + tid * 4;
  ushort4 uv = *(const ushort4*)(in + base);
  float4 xv = {bf2f(uv.x), bf2f(uv.y), bf2f(uv.z), bf2f(uv.w)};
  float sum = xv.x + xv.y + xv.z + xv.w;
  float ss = xv.x * xv.x + xv.y * xv.y + xv.z * xv.z + xv.w * xv.w;
#pragma unroll
  for (int off = 32; off >= 1; off >>= 1) {
    sum += __shfl_down(sum, off, 64);
    ss += __shfl_down(ss, off, 64);
  }
  __shared__ float s1[4], s2[4];
  if ((tid & 63) == 0) { s1[tid >> 6] = sum; s2[tid >> 6] = ss; }
  __syncthreads();
  sum = s1[0] + s1[1] + s1[2] + s1[3];
  ss = s2[0] + s2[1] + s2[2] + s2[3];
  float mu = sum * (1.f / Cn);
  float var = ss * (1.f / Cn) - mu * mu;
  float rstd = rsqrtf(var + 1e-5f);
  float4 gv = *(const float4*)(g + tid * 4);
  float4 bv = *(const float4*)(bb + tid * 4);
  ushort4 o;
  o.x = f2bf((xv.x - mu) * rstd * gv.x + bv.x);
  o.y = f2bf((xv.y - mu) * rstd * gv.y + bv.y);
  o.z = f2bf((xv.z - mu) * rstd * gv.z + bv.z);
  o.w = f2bf((xv.w - mu) * rstd * gv.w + bv.w);
  *(ushort4*)(out + base) = o;
}

extern "C" void kernel_launch(void* const* d_in, const int* in_sizes, int n_in,
                              void* d_out, int out_size, void* d_ws, size_t ws_size,
                              hipStream_t stream) {
  const float* x   = (const float*)d_in[0];
  const float* tmk = (const float*)d_in[1];
  const float* tmv = (const float*)d_in[2];
  const float* tmr = (const float*)d_in[3];
  const float* td  = (const float*)d_in[4];
  const float* tf  = (const float*)d_in[5];
  const float* Wk  = (const float*)d_in[6];
  const float* Wv  = (const float*)d_in[7];
  const float* Wr  = (const float*)d_in[8];
  const float* Wo  = (const float*)d_in[9];
  const float* lng = (const float*)d_in[10];
  const float* lnb = (const float*)d_in[11];
  float* out = (float*)d_out;

  char* ws = (char*)d_ws;
  const size_t MB = 1024 * 1024;
  unsigned short* wbf  = (unsigned short*)(ws);              // 8 MB (4 weights bf16)
  unsigned short* xk   = (unsigned short*)(ws + 8 * MB);     // 32 MB
  unsigned short* xv_  = (unsigned short*)(ws + 40 * MB);    // 32 MB
  unsigned short* xr   = (unsigned short*)(ws + 72 * MB);    // 32 MB
  unsigned short* bufK = (unsigned short*)(ws + 104 * MB);   // 32 MB
  unsigned short* bufV = (unsigned short*)(ws + 136 * MB);   // 32 MB
  unsigned short* bufR = (unsigned short*)(ws + 168 * MB);   // 32 MB
  unsigned short* preLN = xk;                                // reuse
  unsigned short* lnout = xv_;                               // reuse
  float* chunkS = (float*)(ws + 200 * MB);                   // 1 MB

  const int gemm_grid = (Mn / 256) * (Cn / 256);  // 256
  const int mix_grid = Mn * (Cn / 4) / 256;       // 16384

  wconv_kernel<<<4 * Cn * Cn / 4 / 256, 256, 0, stream>>>(Wk, Wv, Wr, Wo, wbf);
  mix3_kernel<<<mix_grid, 256, 0, stream>>>(x, tmk, tmv, tmr, xk, xv_, xr);

  gemm1b<true><<<gemm_grid, 512, 0, stream>>>(xk,  wbf + 0 * (size_t)Cn * Cn, bufK);
  gemm1b<true><<<gemm_grid, 512, 0, stream>>>(xv_, wbf + 1 * (size_t)Cn * Cn, bufV);
  gemm1b<true><<<gemm_grid, 512, 0, stream>>>(xr,  wbf + 2 * (size_t)Cn * Cn, bufR);

  scan_phase1<<<Bsz * Hn * NC, 64, 0, stream>>>(bufK, bufV, td, chunkS);
  scan_phase2<<<Bsz * Hn, 64, 0, stream>>>(td, chunkS);
  scan_phase3<<<Bsz * Hn * NC, 64, 0, stream>>>(bufK, bufV, bufR, td, tf, chunkS, preLN);

  ln_kernel<<<Mn, 256, 0, stream>>>(preLN, lng, lnb, lnout);

  gemm1b<false><<<gemm_grid, 512, 0, stream>>>(lnout, wbf + 3 * (size_t)Cn * Cn, out);

  (void)in_sizes; (void)n_in; (void)out_size; (void)ws_size;
}